// Round 1
// baseline (15.928 us; speedup 1.0000x reference)
//
#include <hip/hip_runtime.h>
#include <math.h>

#define PI_F 3.14159265358979323846f

// Problem constants (from reference): B=32, C=16, H=W=256, K=256
constexpr int NB = 32;
constexpr int NK = 256;
constexpr int NC = 16;
constexpr int NHW = 256 * 256;

// One thread per (b,k) row. Grid = B*K/64 = 128 blocks of 64 (1 wave each).
__global__ __launch_bounds__(64) void vein_rows(
        const float* __restrict__ output,
        const int*   __restrict__ mask,
        const int*   __restrict__ ind,
        const float* __restrict__ target,
        float*       __restrict__ ws) {
    int row = blockIdx.x * 64 + threadIdx.x;     // 0 .. 8191
    int b   = row >> 8;                          // row / NK

    int m   = mask[row];
    int idx = ind[row];

    float num = 0.0f;
    float cnt = 0.0f;

    if (m > 0) {
        cnt = 1.0f;

        // pred[c] = output[b, c, idx]  (scattered gather, stride NHW floats)
        float pred[16];
        const float* ob = output + (size_t)b * NC * NHW + (size_t)idx;
        #pragma unroll
        for (int c = 0; c < NC; ++c) pred[c] = ob[(size_t)c * NHW];

        // tgt: contiguous 16 floats
        float tgt[16];
        const float4* t4 = reinterpret_cast<const float4*>(target + (size_t)row * NC);
        #pragma unroll
        for (int q = 0; q < 4; ++q) {
            float4 v = t4[q];
            tgt[4*q+0] = v.x; tgt[4*q+1] = v.y; tgt[4*q+2] = v.z; tgt[4*q+3] = v.w;
        }

        // polar -> cartesian (mask==1 so masked multiply is identity)
        float px[8], py[8], tx[8], ty[8];
        const float d2r = PI_F / 180.0f;
        #pragma unroll
        for (int i = 0; i < 8; ++i) {
            float pa = pred[2*i+1] * d2r;
            px[i] = pred[2*i] * cosf(pa);
            py[i] = pred[2*i] * sinf(pa);
            float ta = tgt[2*i+1] * d2r;
            tx[i] = tgt[2*i] * cosf(ta);
            ty[i] = tgt[2*i] * sinf(ta);
        }

        // projection result (cartesian)
        float qx[8], qy[8];
        qx[0] = tx[0]; qy[0] = ty[0];     // TRUE_KP = {0,3,7}
        qx[3] = tx[3]; qy[3] = ty[3];
        qx[7] = tx[7]; qy[7] = ty[7];

        const int segs[5] = {1, 2, 4, 5, 6};
        #pragma unroll
        for (int s = 0; s < 5; ++s) {
            int j = segs[s];
            float ax = tx[j-1], ay = ty[j-1];
            float bx = tx[j],   by = ty[j];
            float cx = tx[j+1], cy = ty[j+1];
            float pxx = px[j],  pyy = py[j];

            // closest on segment a->b
            float abx = bx - ax, aby = by - ay;
            float t1 = ((pxx-ax)*abx + (pyy-ay)*aby) / (abx*abx + aby*aby);
            t1 = fminf(fmaxf(t1, 0.0f), 1.0f);
            float c1x = ax + t1*abx, c1y = ay + t1*aby;
            float dx1 = pxx - c1x, dy1 = pyy - c1y;
            float d1 = sqrtf(dx1*dx1 + dy1*dy1);

            // closest on segment b->c
            float bcx = cx - bx, bcy = cy - by;
            float t2 = ((pxx-bx)*bcx + (pyy-by)*bcy) / (bcx*bcx + bcy*bcy);
            t2 = fminf(fmaxf(t2, 0.0f), 1.0f);
            float c2x = bx + t2*bcx, c2y = by + t2*bcy;
            float dx2 = pxx - c2x, dy2 = pyy - c2y;
            float d2 = sqrtf(dx2*dx2 + dy2*dy2);

            bool use2 = d2 < d1;                 // NaN -> false, matches jnp '<'
            float bestx = use2 ? c2x : c1x;
            float besty = use2 ? c2y : c1y;

            bool deg = (ax == cx) && (ay == cy); // all(tm1 == tp1)
            qx[j] = deg ? bx : bestx;
            qy[j] = deg ? by : besty;
        }

        // cartesian -> polar, accumulate L1 vs pred
        #pragma unroll
        for (int i = 0; i < 8; ++i) {
            float d = sqrtf(qx[i]*qx[i] + qy[i]*qy[i]);
            float a = atan2f(qy[i], qx[i]) * (180.0f / PI_F);
            if (a < 0.0f) a += 360.0f;
            num += fabsf(pred[2*i]   - d);
            num += fabsf(pred[2*i+1] - a);
        }
    }

    // wave-64 reduce (block == 1 wave)
    #pragma unroll
    for (int off = 32; off > 0; off >>= 1) {
        num += __shfl_down(num, off, 64);
        cnt += __shfl_down(cnt, off, 64);
    }
    if (threadIdx.x == 0) {
        ws[blockIdx.x]       = num;   // 128 numerator partials
        ws[128 + blockIdx.x] = cnt;   // 128 mask-count partials
    }
}

__global__ __launch_bounds__(64) void vein_final(
        const float* __restrict__ ws, float* __restrict__ out) {
    int t = threadIdx.x;
    float num = ws[t] + ws[t + 64];
    float cnt = ws[128 + t] + ws[128 + t + 64];
    #pragma unroll
    for (int off = 32; off > 0; off >>= 1) {
        num += __shfl_down(num, off, 64);
        cnt += __shfl_down(cnt, off, 64);
    }
    if (t == 0) out[0] = num / (16.0f * cnt + 1e-4f);
}

extern "C" void kernel_launch(void* const* d_in, const int* in_sizes, int n_in,
                              void* d_out, int out_size, void* d_ws, size_t ws_size,
                              hipStream_t stream) {
    const float* output = (const float*)d_in[0];
    const int*   mask   = (const int*)d_in[1];
    const int*   ind    = (const int*)d_in[2];   // jax default: int64 request -> int32
    const float* target = (const float*)d_in[3];
    float* out = (float*)d_out;
    float* ws  = (float*)d_ws;

    vein_rows<<<(NB * NK) / 64, 64, 0, stream>>>(output, mask, ind, target, ws);
    vein_final<<<1, 64, 0, stream>>>(ws, out);
}